// Round 8
// baseline (885.307 us; speedup 1.0000x reference)
//
#include <hip/hip_runtime.h>
#include <math.h>

// GridLSTM one-flag-per-cell dataflow, fused f16 weights. V=50000,E=300,H=128,L=32,B=8.
// 256 blocks x 256 threads. bid = c*32 + i (i = grid row, c = t-slice chunk 0..7).
// gates = WU@ho_up + WL@ho_left + (Pproj+b) + Hypproj + upok*bU + lfok*bL
// with WU/WL precomputed f16x2 on device, consumed via v_dot2_f32_f16.
//
// R8 = R7 (573us) + three serial-path cuts (no transport changes):
//   1. ONE per-block flag (64B-isolated, fired by wave 0, NO barrier/drain) -
//      tags carry data correctness (R7-proven, zero retries measured), so
//      per-wave flags are redundant. Spin fan-in 60 -> 15 lanes; flag-line
//      contention /4 (R7 had 4 flags per cacheline hammered chip-wide).
//   2. Intra-wave K-split: thread = (tqg = tid>>3, ksg = tid&7); the 8 K-seg
//      partials of a gate live in 8 ADJACENT LANES -> reduce with 3 shfl_xor,
//      deleting the red/red2 LDS round trip (43KB) and one __syncthreads.
//      Elementwise runs lane-local: b = ksg, hidden unit u = tqg.
//   3. Hypproj prefetch hoisted above the flag spin (depends only on j).

typedef _Float16 h2 __attribute__((ext_vector_type(2)));
typedef unsigned long long ull;

__device__ __forceinline__ h2 pk_f16(float a, float b) {
    return __builtin_bit_cast(h2, __builtin_amdgcn_cvt_pkrtz(a, b));
}

// ---------------- workspace layout (float words) — total 1,321,984 (R7-proven) ----
#define HYP_OFF   0            // Hypproj [32 j][8 b][1024]            (atomic f32) 1MB
#define WP_OFF    262144       // fused wts packed h2 [1024 g][256]    (atomic u32) 1MB
#define B_OFF     524288       // bU[1024] | bL[1024]
#define INITF_OFF 526336       // InitF [p*4] (1024 floats)
#define WF_OFF    527360       // per-BLOCK flags [bid*16] (4096 floats, 64B stride)
#define HOT_OFF   531456       // Ho tagged u64 [4 dep][32 j][8 b][128 kk] (1MB)
#define COT_OFF   793600       // Co tagged u64 [4 dep][32 j][8 b][256 t]  (2MB)
#define HOF_OFF   1317888      // final ho(31,31) tagged u64 [8 b][256 t]  (16KB)
// end = 1321984 floats = 5.288 MB

#define BASE 0xAAAAAAAAu

__device__ __forceinline__ float sigm(float x) { return 1.f / (1.f + __expf(-x)); }
__device__ __forceinline__ float tanh_fast(float x) { return 1.f - 2.f / (__expf(2.f * x) + 1.f); }

__device__ __forceinline__ unsigned ld_flag(const unsigned* p) {
    return __hip_atomic_load(p, __ATOMIC_RELAXED, __HIP_MEMORY_SCOPE_AGENT);
}
__device__ __forceinline__ void st_flag(unsigned* p, unsigned v) {
    __hip_atomic_store(p, v, __ATOMIC_RELAXED, __HIP_MEMORY_SCOPE_AGENT);
}
__device__ __forceinline__ float ld_f32(const float* p) {
    unsigned u = __hip_atomic_load((const unsigned*)p, __ATOMIC_RELAXED, __HIP_MEMORY_SCOPE_AGENT);
    return __uint_as_float(u);
}
__device__ __forceinline__ void st_f32(float* p, float v) {
    __hip_atomic_store((unsigned*)p, __float_as_uint(v), __ATOMIC_RELAXED, __HIP_MEMORY_SCOPE_AGENT);
}
__device__ __forceinline__ void st_u32(unsigned* p, unsigned v) {
    __hip_atomic_store(p, v, __ATOMIC_RELAXED, __HIP_MEMORY_SCOPE_AGENT);
}
__device__ __forceinline__ ull ld_u64(const ull* p) {
    return __hip_atomic_load(p, __ATOMIC_RELAXED, __HIP_MEMORY_SCOPE_AGENT);
}
__device__ __forceinline__ void st_u64(ull* p, ull v) {
    __hip_atomic_store(p, v, __ATOMIC_RELAXED, __HIP_MEMORY_SCOPE_AGENT);
}
__device__ __forceinline__ void wait_ge(const unsigned* f, unsigned target) {
    long spins = 0;
    while ((ld_flag(f) - BASE) < target) {
        __builtin_amdgcn_s_sleep(1);
        if (++spins > (1L << 22)) break;   // failsafe: wrong answer > hang
    }
}
__device__ __forceinline__ void drain_vmem() {
    asm volatile("s_waitcnt vmcnt(0)" ::: "memory");
}

__global__ void __launch_bounds__(256, 1) grid_lstm_kernel(
    const int* __restrict__ premise, const int* __restrict__ hypothesis,
    const float* __restrict__ emb,
    const float* __restrict__ W_ih, const float* __restrict__ b_ih,
    const float* __restrict__ W_hh, const float* __restrict__ b_hh,
    const float* __restrict__ W_ch, const float* __restrict__ b_ch,
    const float* __restrict__ W_cc, const float* __restrict__ b_cc,
    const float* __restrict__ W1, const float* __restrict__ b1,
    const float* __restrict__ W2, const float* __restrict__ b2,
    const float* __restrict__ W3, const float* __restrict__ b3,
    float* __restrict__ out, float* __restrict__ ws)
{
    __shared__ h2    hAB[2048];      // f16 [8 b][256 kk]: kk<128 up, kk>=128 left (8KB)
    __shared__ float sCo[2048];      // f32 co_side [8 b][256] (8KB)
    __shared__ float ppL[1024];      // Pproj slice [8 b][128 g], g=(a<<5)|s (4KB)
    __shared__ float scr[4800];      // init embs / final MLP scratch (19.2KB)

    const int tid = threadIdx.x;
    const int bid = blockIdx.x;
    const int i   = bid & 31;       // grid row
    const int c   = bid >> 5;       // t-slice chunk

    float*    Hypproj = ws + HYP_OFF;
    unsigned* WP      = (unsigned*)(ws + WP_OFF);
    float*    BU      = ws + B_OFF;
    float*    BL      = ws + B_OFF + 1024;
    unsigned* InitF   = (unsigned*)(ws + INITF_OFF);   // [p*4]
    unsigned* WF      = (unsigned*)(ws + WF_OFF);      // [bid*16] (64B isolated)
    ull*      HoT     = (ull*)(ws + HOT_OFF);          // {tag<<32 | f16x2}
    ull*      CoT     = (ull*)(ws + COT_OFF);          // {tag<<32 | f32}
    ull*      HoF     = (ull*)(ws + HOF_OFF);          // {tag<<32 | f32}

    // GEMM/elementwise coords: ksg = K-seg AND batch (intra-wave 8-group), tqg = hidden unit
    const int ksg = tid & 7, tqg = tid >> 3;

    // ================= Init A: Pproj (LDS) + Hypproj for this block's gate rows ====
    {
        float* embs = scr;   // [2 sides][8][300] = 4800 floats
        for (int idx = tid; idx < 4800; idx += 256) {
            int side = idx / 2400, rem = idx - side * 2400;
            int b = rem / 300, e = rem - b * 300;
            const int* toks = side ? hypothesis : premise;
            embs[idx] = emb[(long)toks[b * 32 + i] * 300 + e];
        }
        __syncthreads();
        #pragma unroll 1
        for (int q = 0; q < 4; q++) {
            const int oo = tid + q * 256;
            const int b = oo >> 7, g = oo & 127;
            const int gr = (g >> 5) * 256 + c * 32 + (g & 31);   // t-sliced gate row
            float accP = b_ih[gr] + b_hh[gr];
            float accH = 0.f;
            const float* wp = W_ih + (long)gr * 600;
            const float* eP = embs + b * 300;
            const float* eH = embs + 2400 + b * 300;
            for (int e = 0; e < 300; e += 4) {
                float4 w1 = *(const float4*)(wp + e);
                float4 w2v = *(const float4*)(wp + 300 + e);
                float4 p4 = *(const float4*)(eP + e);
                float4 h4 = *(const float4*)(eH + e);
                accP += w1.x * p4.x + w1.y * p4.y + w1.z * p4.z + w1.w * p4.w;
                accH += w2v.x * h4.x + w2v.y * h4.y + w2v.z * h4.z + w2v.w * h4.w;
            }
            st_f32(&Hypproj[i * 8192 + b * 1024 + gr], accH);     // cross-block
            ppL[b * 128 + g] = accP;                              // block-local
        }
        __syncthreads();   // embs (scr) free
    }

    // ================= Init B: fused weight rows [4*bid, 4*bid+4) =================
    {
        const int tr = tid >> 6, col = (tid & 63) * 4;
        const int r  = bid * 4 + tr;
        float u[4] = {0.f, 0.f, 0.f, 0.f}, l[4] = {0.f, 0.f, 0.f, 0.f};
        const float* whU = W_hh + (long)r * 256;
        const float* whL = whU + 128;
        for (int k = 0; k < 128; k++) {
            const float wu = whU[k], wl = whL[k];
            float4 wc = *(const float4*)(W_ch + (long)k * 256 + col);
            u[0] += wu * wc.x; u[1] += wu * wc.y; u[2] += wu * wc.z; u[3] += wu * wc.w;
            l[0] += wl * wc.x; l[1] += wl * wc.y; l[2] += wl * wc.z; l[3] += wl * wc.w;
        }
        unsigned* wrow = WP + (long)r * 256;
        st_u32(&wrow[col / 2],       __builtin_bit_cast(unsigned, __builtin_amdgcn_cvt_pkrtz(u[0], u[1])));
        st_u32(&wrow[col / 2 + 1],   __builtin_bit_cast(unsigned, __builtin_amdgcn_cvt_pkrtz(u[2], u[3])));
        st_u32(&wrow[128 + col / 2],     __builtin_bit_cast(unsigned, __builtin_amdgcn_cvt_pkrtz(l[0], l[1])));
        st_u32(&wrow[128 + col / 2 + 1], __builtin_bit_cast(unsigned, __builtin_amdgcn_cvt_pkrtz(l[2], l[3])));
        if ((tid & 63) == 0) {   // bias projections for this row
            float su = 0.f, sl = 0.f;
            for (int k = 0; k < 128; k++) { su += whU[k] * b_ch[k]; sl += whL[k] * b_ch[k]; }
            st_f32(&BU[r], su); st_f32(&BL[r], sl);
        }
    }
    drain_vmem();
    __syncthreads();
    if (tid == 0) st_flag(&InitF[bid * 4], BASE + 1u);

    // ---- wait ALL inits (covers every Hypproj row + all fused weights) ----
    wait_ge(&InitF[tid * 4], 1u);
    __syncthreads();

    // ---- load fused weight slice -> registers (f16x2), W_cc slice (fp32) ----
    h2 w[4][32];                  // 128 VGPRs; gate rows (a*256 + c*32 + tqg), K-seg ksg
    #pragma unroll
    for (int a = 0; a < 4; a++) {
        const unsigned* src = WP + (long)(a * 256 + c * 32 + tqg) * 256 + ksg * 32;
        #pragma unroll
        for (int m = 0; m < 16; m++) {
            ull u2 = ld_u64((const ull*)(src + m * 2));
            w[a][2 * m]     = __builtin_bit_cast(h2, (unsigned)u2);
            w[a][2 * m + 1] = __builtin_bit_cast(h2, (unsigned)(u2 >> 32));
        }
    }
    float4 w3[8];                 // 32 VGPRs: W_cc row (c&3)*32+tqg, K-seg ksg*32..+32
    {
        const float* wr = W_cc + (long)((c & 3) * 32 + tqg) * 256 + ksg * 32;
        #pragma unroll
        for (int m = 0; m < 8; m++) w3[m] = *(const float4*)(wr + m * 4);
    }
    float bUv[4], bLv[4];
    #pragma unroll
    for (int a = 0; a < 4; a++) {
        bUv[a] = ld_f32(&BU[a * 256 + c * 32 + tqg]);
        bLv[a] = ld_f32(&BL[a * 256 + c * 32 + tqg]);
    }

    // ================= Wavefront: row i walks j = 0..31 =================
    #pragma unroll 1
    for (int j = 0; j < 32; j++) {
        const bool upok = (i > 0), lfok = (j > 0);
        const bool cok  = (c < 4) ? upok : lfok;
        const int  jl   = lfok ? (j - 1) : 0;

        const unsigned upTag = (unsigned)((i - 1) * 32 + j + 1);   // tag of cell (i-1,j)
        const unsigned lfTag = (unsigned)(i * 32 + j);             // tag of cell (i,j-1)
        const unsigned coTag = (c < 4) ? upTag : lfTag;

        // ---- Hypproj prefetch BEFORE the spin (depends only on j) ----
        float hyv[4];
        #pragma unroll
        for (int a = 0; a < 4; a++)
            hyv[a] = ld_f32(&Hypproj[j * 8192 + ksg * 1024 + a * 256 + c * 32 + tqg]);

        // ---- dependency wait: 15 lanes, one per-BLOCK flag each (throttle only) ----
        // lanes 0..7 : up blocks (cc*32 + i-1), target j+1
        // lanes 8..14: left siblings (cc*32 + i), cc != c, target j
        if (upok && tid < 8) {
            wait_ge(&WF[(tid * 32 + (i - 1)) * 16], (unsigned)(j + 1));
        } else if (lfok && tid >= 8 && tid < 15) {
            int s = tid - 8;
            int cc = s + ((s >= c) ? 1 : 0);      // skip self
            wait_ge(&WF[(cc * 32 + i) * 16], (unsigned)j);
        }
        __syncthreads();

        // ---- BATCHED tagged loads + predicated retry (expected 1 round) ----
        const ull* HoUpT = HoT + (size_t)(((i - 1) & 3) * 32 + j) * 1024;
        const ull* HoLfT = HoT + (size_t)((i & 3) * 32 + jl) * 1024;
        const ull* CoST  = (c < 4)
            ? CoT + (size_t)(((i - 1) & 3) * 32 + j) * 2048
            : CoT + (size_t)((i & 3) * 32 + jl) * 2048;
        const int hi = tid >> 7, kk = tid & 127;   // staging mapping (decoupled from GEMM)

        ull uv[4] = {0, 0, 0, 0}, lv[4] = {0, 0, 0, 0};
        ull cv[8] = {0, 0, 0, 0, 0, 0, 0, 0};
        unsigned pend = (upok ? 0x000Fu : 0u) | (lfok ? 0x00F0u : 0u) | (cok ? 0xFF00u : 0u);
        long spins = 0;
        while (pend) {
            #pragma unroll
            for (int r = 0; r < 4; r++) {
                if (pend & (1u << r))        uv[r] = ld_u64(HoUpT + (2 * r + hi) * 128 + kk);
                if (pend & (0x10u << r))     lv[r] = ld_u64(HoLfT + (2 * r + hi) * 128 + kk);
                if (pend & (0x100u << 2*r))  cv[2*r]   = ld_u64(CoST + (2 * r + hi) * 256 + 2 * kk);
                if (pend & (0x200u << 2*r))  cv[2*r+1] = ld_u64(CoST + (2 * r + hi) * 256 + 2 * kk + 1);
            }
            #pragma unroll
            for (int r = 0; r < 4; r++) {
                if ((pend & (1u << r))       && (unsigned)(uv[r] >> 32) == upTag)      pend &= ~(1u << r);
                if ((pend & (0x10u << r))    && (unsigned)(lv[r] >> 32) == lfTag)      pend &= ~(0x10u << r);
                if ((pend & (0x100u << 2*r)) && (unsigned)(cv[2*r] >> 32) == coTag)    pend &= ~(0x100u << 2*r);
                if ((pend & (0x200u << 2*r)) && (unsigned)(cv[2*r+1] >> 32) == coTag)  pend &= ~(0x200u << 2*r);
            }
            if (pend) {
                __builtin_amdgcn_s_sleep(1);
                if (++spins > (1L << 22)) break;   // failsafe: wrong answer > hang
            }
        }
        __builtin_amdgcn_sched_barrier(0);   // keep loads/checks before LDS writes
        #pragma unroll
        for (int r = 0; r < 4; r++) {
            const int b = 2 * r + hi;
            hAB[b * 256 + kk]       = __builtin_bit_cast(h2, (unsigned)uv[r]);   // 0u == (0,0)
            hAB[b * 256 + 128 + kk] = __builtin_bit_cast(h2, (unsigned)lv[r]);
            sCo[b * 256 + 2 * kk]     = __uint_as_float((unsigned)cv[2*r]);
            sCo[b * 256 + 2 * kk + 1] = __uint_as_float((unsigned)cv[2*r+1]);
        }
        __syncthreads();

        // ---- fused gates GEMM (f16 dot2) + c-path (fp32) ----
        float acc[4][8], a3[8];
        #pragma unroll
        for (int a = 0; a < 4; a++)
            #pragma unroll
            for (int b = 0; b < 8; b++) acc[a][b] = 0.f;
        #pragma unroll
        for (int b = 0; b < 8; b++) a3[b] = 0.f;
        #pragma unroll
        for (int b = 0; b < 8; b++) {
            const h2*    hb = hAB + b * 256 + ksg * 32;
            const float* cb = sCo + b * 256 + ksg * 32;
            #pragma unroll
            for (int m4 = 0; m4 < 8; m4++) {
                uint4 hu = *(const uint4*)(hb + m4 * 4);
                h2 h0 = __builtin_bit_cast(h2, hu.x);
                h2 h1 = __builtin_bit_cast(h2, hu.y);
                h2 h2v = __builtin_bit_cast(h2, hu.z);
                h2 h3 = __builtin_bit_cast(h2, hu.w);
                #pragma unroll
                for (int a = 0; a < 4; a++) {
                    acc[a][b] = __builtin_amdgcn_fdot2(w[a][m4 * 4],     h0,  acc[a][b], false);
                    acc[a][b] = __builtin_amdgcn_fdot2(w[a][m4 * 4 + 1], h1,  acc[a][b], false);
                    acc[a][b] = __builtin_amdgcn_fdot2(w[a][m4 * 4 + 2], h2v, acc[a][b], false);
                    acc[a][b] = __builtin_amdgcn_fdot2(w[a][m4 * 4 + 3], h3,  acc[a][b], false);
                }
                float4 cv4 = *(const float4*)(cb + m4 * 4);
                a3[b] += w3[m4].x * cv4.x + w3[m4].y * cv4.y + w3[m4].z * cv4.z + w3[m4].w * cv4.w;
            }
        }

        // ---- intra-wave K-reduction: lanes tqg*8 + (0..7) hold the 8 partials ----
        #pragma unroll
        for (int a = 0; a < 4; a++)
            #pragma unroll
            for (int b = 0; b < 8; b++) {
                float v = acc[a][b];
                v += __shfl_xor(v, 1);
                v += __shfl_xor(v, 2);
                v += __shfl_xor(v, 4);
                acc[a][b] = v;
            }
        #pragma unroll
        for (int b = 0; b < 8; b++) {
            float v = a3[b];
            v += __shfl_xor(v, 1);
            v += __shfl_xor(v, 2);
            v += __shfl_xor(v, 4);
            a3[b] = v;
        }

        // ---- elementwise (lane-local: b = ksg, hidden u = tqg) + tagged publish ----
        {
            float g4[4];
            #pragma unroll
            for (int a = 0; a < 4; a++) {
                float s = acc[a][ksg] + ppL[ksg * 128 + a * 32 + tqg] + hyv[a];
                if (upok) s += bUv[a];
                if (lfok) s += bLv[a];
                g4[a] = s;
            }
            float ci = a3[ksg];
            if (cok) ci += b_cc[(c & 3) * 32 + tqg];
            const float cnew = sigm(g4[1]) * ci + sigm(g4[0]) * tanh_fast(g4[2]);
            const float hnew = sigm(g4[3]) * tanh_fast(cnew);

            const unsigned myTag = (unsigned)(i * 32 + j + 1);
            const ull tagHi = ((ull)myTag) << 32;
            const int slot = (i & 3) * 32 + j;

            st_u64(&CoT[(size_t)slot * 2048 + ksg * 256 + c * 32 + tqg],
                   tagHi | (ull)__float_as_uint(cnew));
            const float hOdd = __shfl_xor(hnew, 8);   // partner: tqg^1, same ksg
            if ((tqg & 1) == 0)
                st_u64(&HoT[(size_t)slot * 1024 + ksg * 128 + c * 16 + (tqg >> 1)],
                       tagHi | (ull)__builtin_bit_cast(unsigned, pk_f16(hnew, hOdd)));
            if (i == 31 && j == 31)
                st_u64(&HoF[ksg * 256 + c * 32 + tqg],
                       tagHi | (ull)__float_as_uint(hnew));   // full-precision corner
        }
        // single per-block flag, wave0-fired, NO drain/barrier (tags carry data).
        if (tid == 0) st_flag(&WF[bid * 16], BASE + (unsigned)(j + 1));
    }

    // ================= Final: condense ho(31,31) + MLP + softmax (bid 31) ==========
    if (bid == 31) {
        if (tid < 8) wait_ge(&WF[(tid * 32 + 31) * 16], 32u);
        __syncthreads();
        const unsigned fTag = 1024u;   // 31*32 + 31 + 1
        float hov[8] = {0.f, 0.f, 0.f, 0.f, 0.f, 0.f, 0.f, 0.f};
        unsigned pf = 0xFFu;
        long spins = 0;
        while (pf) {
            ull tv[8];
            #pragma unroll
            for (int r = 0; r < 8; r++)
                if (pf & (1u << r)) tv[r] = ld_u64(HoF + r * 256 + tid);
            #pragma unroll
            for (int r = 0; r < 8; r++)
                if ((pf & (1u << r)) && (unsigned)(tv[r] >> 32) == fTag) {
                    hov[r] = __uint_as_float((unsigned)tv[r]);
                    pf &= ~(1u << r);
                }
            if (pf) {
                __builtin_amdgcn_s_sleep(1);
                if (++spins > (1L << 22)) break;   // failsafe
            }
        }
        #pragma unroll
        for (int r = 0; r < 8; r++) sCo[r * 256 + tid] = hov[r];
        __syncthreads();
        // condense: hcond[b][o] = b_ch[o] + W_ch[o,:] @ ho[b,:]
        #pragma unroll 1
        for (int q = 0; q < 4; q++) {
            const int oo = tid + q * 256;
            const int b = oo >> 7, o = oo & 127;
            float a = b_ch[o];
            const float* wr = W_ch + (long)o * 256;
            const float* x = sCo + b * 256;
            for (int k = 0; k < 256; k += 4) {
                float4 wv = *(const float4*)(wr + k);
                float4 xv = *(const float4*)(x + k);
                a += wv.x * xv.x + wv.y * xv.y + wv.z * xv.z + wv.w * xv.w;
            }
            ppL[b * 128 + o] = a;
        }
        __syncthreads();
        float* m1 = scr;          // [8][128]
        float* m2 = scr + 1024;   // [8][128]
        for (int idx = tid; idx < 1024; idx += 256) {
            int b = idx >> 7, o = idx & 127;
            float a = b1[o];
            const float* wr = W1 + o * 128; const float* x = ppL + b * 128;
            for (int k = 0; k < 128; k++) a += wr[k] * x[k];
            m1[idx] = fmaxf(a, 0.f);
        }
        __syncthreads();
        for (int idx = tid; idx < 1024; idx += 256) {
            int b = idx >> 7, o = idx & 127;
            float a = b2[o];
            const float* wr = W2 + o * 128; const float* x = m1 + b * 128;
            for (int k = 0; k < 128; k++) a += wr[k] * x[k];
            m2[idx] = fmaxf(a, 0.f);
        }
        __syncthreads();
        if (tid < 8) {
            const int b = tid;
            float lg[3];
            for (int cc = 0; cc < 3; cc++) {
                float a = b3[cc];
                const float* wr = W3 + cc * 128; const float* x = m2 + b * 128;
                for (int k = 0; k < 128; k++) a += wr[k] * x[k];
                lg[cc] = a;
            }
            float m = fmaxf(lg[0], fmaxf(lg[1], lg[2]));
            float e0 = expf(lg[0] - m), e1 = expf(lg[1] - m), e2 = expf(lg[2] - m);
            float s = e0 + e1 + e2;
            out[b * 3 + 0] = e0 / s;
            out[b * 3 + 1] = e1 / s;
            out[b * 3 + 2] = e2 / s;
        }
    }
}

extern "C" void kernel_launch(void* const* d_in, const int* in_sizes, int n_in,
                              void* d_out, int out_size, void* d_ws, size_t ws_size,
                              hipStream_t stream) {
    const int*   premise    = (const int*)d_in[0];
    const int*   hypothesis = (const int*)d_in[1];
    const float* emb        = (const float*)d_in[2];
    const float* W_ih       = (const float*)d_in[3];
    const float* b_ih       = (const float*)d_in[4];
    const float* W_hh       = (const float*)d_in[5];
    const float* b_hh       = (const float*)d_in[6];
    const float* W_ch       = (const float*)d_in[7];
    const float* b_ch       = (const float*)d_in[8];
    const float* W_cc       = (const float*)d_in[9];
    const float* b_cc       = (const float*)d_in[10];
    const float* W1         = (const float*)d_in[11];
    const float* b1         = (const float*)d_in[12];
    const float* W2         = (const float*)d_in[13];
    const float* b2         = (const float*)d_in[14];
    const float* W3         = (const float*)d_in[15];
    const float* b3         = (const float*)d_in[16];
    float* out = (float*)d_out;
    float* ws  = (float*)d_ws;

    (void)in_sizes; (void)n_in; (void)out_size; (void)ws_size;

    grid_lstm_kernel<<<dim3(256), dim3(256), 0, stream>>>(
        premise, hypothesis, emb, W_ih, b_ih, W_hh, b_hh,
        W_ch, b_ch, W_cc, b_cc, W1, b1, W2, b2, W3, b3, out, ws);
}